// Round 2
// baseline (538.669 us; speedup 1.0000x reference)
//
#include <hip/hip_runtime.h>

#define B_ 256
#define K_ 512
#define D_ 256
#define H_ 256
#define NROWS (B_*K_)          // 131072
#define LNEPS 1e-5f

// =================== FAST PATH (needs ws >= 128 MB) ===================

// Kernel A: LayerNorm -> xln in d_ws. One wave per row (lane = 4 d's).
__global__ __launch_bounds__(512) void ln_kernel(
    const float* __restrict__ slots, const float* __restrict__ gamma,
    const float* __restrict__ beta, float* __restrict__ xln)
{
    const int t = threadIdx.x;
    const int lane = t & 63;
    const int row = blockIdx.x * 8 + (t >> 6);
    const float4 x = ((const float4*)(slots + (size_t)row * D_))[lane];
    float s = x.x + x.y + x.z + x.w;
    #pragma unroll
    for (int off = 1; off < 64; off <<= 1) s += __shfl_xor(s, off, 64);
    const float mean = s * (1.f/256.f);
    const float4 dx = {x.x-mean, x.y-mean, x.z-mean, x.w-mean};
    float q = dx.x*dx.x + dx.y*dx.y + dx.z*dx.z + dx.w*dx.w;
    #pragma unroll
    for (int off = 1; off < 64; off <<= 1) q += __shfl_xor(q, off, 64);
    const float rstd = rsqrtf(q * (1.f/256.f) + LNEPS);
    const float4 g = ((const float4*)gamma)[lane];
    const float4 b = ((const float4*)beta)[lane];
    float4 o;
    o.x = dx.x*rstd*g.x + b.x;
    o.y = dx.y*rstd*g.y + b.y;
    o.z = dx.z*rstd*g.z + b.z;
    o.w = dx.w*rstd*g.w + b.w;
    ((float4*)(xln + (size_t)row * D_))[lane] = o;
}

// Kernel B: GEMM + epilogue. Block = 256 threads (4 waves), thread = col.
// 64 rows per block. w1 chunk (32 d x col) in VGPRs, loop-invariant over
// rows; xln broadcast via s_load (uniform address), double-buffered.
__global__ __launch_bounds__(256, 4) void gemm_kernel(
    const float* __restrict__ xln, const float* __restrict__ w1,
    const float* __restrict__ b1, const float* __restrict__ w2,
    const float* __restrict__ b2, const float* __restrict__ u,
    float* __restrict__ out)
{
    __shared__ float red[4][64][2];
    const int t = threadIdx.x;          // col 0..255
    const int lane = t & 63;
    const int wv = t >> 6;
    const int row0 = blockIdx.x * 64;

    float acc[64];
    #pragma unroll
    for (int r = 0; r < 64; ++r) acc[r] = 0.f;

    for (int ch = 0; ch < 8; ++ch) {
        // per-lane w1 chunk: w[dd] = w1[ch*32+dd][col]  (coalesced dword loads)
        float w[32];
        const float* wp = w1 + (size_t)(ch*32) * H_ + t;
        #pragma unroll
        for (int dd = 0; dd < 32; ++dd) w[dd] = wp[(size_t)dd * H_];

        const float* xp = xln + (size_t)row0 * D_ + ch*32;  // uniform
        float xc[32], xn[32];
        #pragma unroll
        for (int dd = 0; dd < 32; ++dd) xc[dd] = xp[dd];
        #pragma unroll
        for (int r = 0; r < 64; ++r) {
            const float* xq = xp + (size_t)((r < 63) ? (r+1) : r) * D_;
            #pragma unroll
            for (int dd = 0; dd < 32; ++dd) xn[dd] = xq[dd];   // prefetch next row
            float a = acc[r];
            #pragma unroll
            for (int dd = 0; dd < 32; ++dd) a = fmaf(xc[dd], w[dd], a);
            acc[r] = a;
            #pragma unroll
            for (int dd = 0; dd < 32; ++dd) xc[dd] = xn[dd];
        }
    }

    // epilogue: bias + relu + w2 dot, reduce 64 lanes then 4 waves
    const float bc  = b1[t];
    const float w20 = w2[2*t + 0];
    const float w21 = w2[2*t + 1];
    #pragma unroll
    for (int r = 0; r < 64; ++r) {
        const float h = fmaxf(acc[r] + bc, 0.f);
        float v0 = h * w20;
        float v1 = h * w21;
        #pragma unroll
        for (int off = 1; off < 64; off <<= 1) {
            v0 += __shfl_xor(v0, off, 64);
            v1 += __shfl_xor(v1, off, 64);
        }
        if (lane == 0) { red[wv][r][0] = v0; red[wv][r][1] = v1; }
    }
    __syncthreads();
    if (t < 64) {
        const int gr = row0 + t;
        const float l0 = b2[0] + red[0][t][0] + red[1][t][0] + red[2][t][0] + red[3][t][0];
        const float l1 = b2[1] + red[0][t][1] + red[1][t][1] + red[2][t][1] + red[3][t][1];
        const float u0 = u[2*gr + 0];
        const float u1 = u[2*gr + 1];
        const float g0 = -logf(-logf(u0));
        const float g1 = -logf(-logf(u1));
        out[gr] = ((l1 + g1) > (l0 + g0)) ? 1.f : 0.f;
        out[NROWS + gr] = 1.f / (1.f + expf(l0 - l1));
    }
}

// =================== FALLBACK (round-1 fused kernel) ===================
__global__ __launch_bounds__(512, 4) void fused_main(
    const float* __restrict__ slots, const float* __restrict__ gamma,
    const float* __restrict__ beta,  const float* __restrict__ w1,
    const float* __restrict__ b1,    const float* __restrict__ w2,
    const float* __restrict__ b2,    const float* __restrict__ u,
    float* __restrict__ out)
{
    __shared__ float smem[64 * D_];
    const int t = threadIdx.x;
    const int row0 = blockIdx.x * 64;
    {
        const int row = t >> 3;
        const int oct = t & 7;
        const float* sp = slots + (size_t)(row0 + row) * D_ + oct * 32;
        float x[32];
        #pragma unroll
        for (int i = 0; i < 8; ++i) {
            float4 v = ((const float4*)sp)[i];
            x[4*i+0] = v.x; x[4*i+1] = v.y; x[4*i+2] = v.z; x[4*i+3] = v.w;
        }
        float s = 0.f;
        #pragma unroll
        for (int i = 0; i < 32; ++i) s += x[i];
        s += __shfl_xor(s, 1, 64); s += __shfl_xor(s, 2, 64); s += __shfl_xor(s, 4, 64);
        const float mean = s * (1.f/256.f);
        float vs = 0.f;
        #pragma unroll
        for (int i = 0; i < 32; ++i) { float dx = x[i] - mean; vs += dx*dx; }
        vs += __shfl_xor(vs, 1, 64); vs += __shfl_xor(vs, 2, 64); vs += __shfl_xor(vs, 4, 64);
        const float rstd = rsqrtf(vs * (1.f/256.f) + LNEPS);
        const int swz = (row & 7) << 2;
        #pragma unroll
        for (int i = 0; i < 8; ++i) {
            const int d  = oct*32 + i*4;
            const int pd = (d & ~31) | ((d & 31) ^ swz);
            float4 gv = *(const float4*)(gamma + d);
            float4 bv = *(const float4*)(beta  + d);
            float4 o;
            o.x = (x[4*i+0]-mean)*rstd*gv.x + bv.x;
            o.y = (x[4*i+1]-mean)*rstd*gv.y + bv.y;
            o.z = (x[4*i+2]-mean)*rstd*gv.z + bv.z;
            o.w = (x[4*i+3]-mean)*rstd*gv.w + bv.w;
            *(float4*)&smem[row*D_ + pd] = o;
        }
    }
    __syncthreads();
    const int lane = t & 63;
    const int wv   = __builtin_amdgcn_readfirstlane(t >> 6);
    const int cb   = wv * 32;
    float acc[32];
    #pragma unroll
    for (int j = 0; j < 32; ++j) acc[j] = b1[cb + j];
    const int swz2 = (lane & 7) << 2;
    const float* w1p = w1 + cb;
    for (int d0 = 0; d0 < D_; d0 += 4) {
        const int pd = (d0 & ~31) | ((d0 & 31) ^ swz2);
        const float4 xv = *(const float4*)&smem[lane*D_ + pd];
        #pragma unroll
        for (int dd = 0; dd < 4; ++dd) {
            const float xd = (dd==0) ? xv.x : (dd==1) ? xv.y : (dd==2) ? xv.z : xv.w;
            const float* wrow = w1p + (size_t)(d0 + dd) * H_;
            #pragma unroll
            for (int j = 0; j < 32; ++j) acc[j] = fmaf(xd, wrow[j], acc[j]);
        }
    }
    float p0 = 0.f, p1 = 0.f;
    #pragma unroll
    for (int j = 0; j < 32; ++j) {
        const float r = fmaxf(acc[j], 0.f);
        p0 = fmaf(r, w2[(cb + j)*2 + 0], p0);
        p1 = fmaf(r, w2[(cb + j)*2 + 1], p1);
    }
    __syncthreads();
    smem[(wv*64 + lane)*2 + 0] = p0;
    smem[(wv*64 + lane)*2 + 1] = p1;
    __syncthreads();
    if (t < 64) {
        float l0 = b2[0], l1 = b2[1];
        #pragma unroll
        for (int w = 0; w < 8; ++w) {
            l0 += smem[(w*64 + t)*2 + 0];
            l1 += smem[(w*64 + t)*2 + 1];
        }
        const int gr = row0 + t;
        const float u0 = u[2*gr + 0];
        const float u1 = u[2*gr + 1];
        const float g0 = -logf(-logf(u0));
        const float g1 = -logf(-logf(u1));
        out[gr] = ((l1 + g1) > (l0 + g0)) ? 1.f : 0.f;
        out[NROWS + gr] = 1.f / (1.f + expf(l0 - l1));
    }
}

// =================== fixup: lower-bound resampling ===================
__global__ __launch_bounds__(512) void fixup(
    const float* __restrict__ rk, float* __restrict__ out)
{
    __shared__ unsigned long long best[8];
    __shared__ int cnts[8];
    const int b = blockIdx.x;
    const int k = threadIdx.x;
    const float m = out[b*K_ + k];
    const unsigned long long ball = __ballot(m != 0.f);
    const int wv = k >> 6;
    const int wcount = __popcll(ball);
    const unsigned kb = __float_as_uint(rk[b*K_ + k]);
    unsigned long long comb = ((unsigned long long)kb << 32) | (unsigned)(K_ - 1 - k);
    #pragma unroll
    for (int off = 32; off; off >>= 1) {
        unsigned long long o = __shfl_down(comb, off, 64);
        if (o > comb) comb = o;
    }
    if ((k & 63) == 0) { best[wv] = comb; cnts[wv] = wcount; }
    __syncthreads();
    if (k == 0) {
        int tot = 0; unsigned long long bc = 0;
        #pragma unroll
        for (int w = 0; w < 8; ++w) { tot += cnts[w]; if (best[w] > bc) bc = best[w]; }
        if (tot == 0) {
            const int kbest = (K_ - 1) - (int)(bc & 0xffffffffu);
            out[b*K_ + kbest] = 1.f;
        }
    }
}

extern "C" void kernel_launch(void* const* d_in, const int* in_sizes, int n_in,
                              void* d_out, int out_size, void* d_ws, size_t ws_size,
                              hipStream_t stream) {
    const float* slots = (const float*)d_in[0];
    const float* gamma = (const float*)d_in[1];
    const float* beta  = (const float*)d_in[2];
    const float* w1    = (const float*)d_in[3];
    const float* b1    = (const float*)d_in[4];
    const float* w2    = (const float*)d_in[5];
    const float* b2    = (const float*)d_in[6];
    const float* u     = (const float*)d_in[7];
    const float* rk    = (const float*)d_in[8];
    float* out = (float*)d_out;

    const size_t need = (size_t)NROWS * D_ * sizeof(float);
    if (ws_size >= need) {
        float* xln = (float*)d_ws;
        hipLaunchKernelGGL(ln_kernel, dim3(NROWS / 8), dim3(512), 0, stream,
                           slots, gamma, beta, xln);
        hipLaunchKernelGGL(gemm_kernel, dim3(NROWS / 64), dim3(256), 0, stream,
                           xln, w1, b1, w2, b2, u, out);
    } else {
        hipLaunchKernelGGL(fused_main, dim3(NROWS / 64), dim3(512), 0, stream,
                           slots, gamma, beta, w1, b1, w2, b2, u, out);
    }
    hipLaunchKernelGGL(fixup, dim3(B_), dim3(512), 0, stream, rk, out);
}

// Round 3
// 256.191 us; speedup vs baseline: 2.1026x; 2.1026x over previous
//
#include <hip/hip_runtime.h>

typedef _Float16 half8 __attribute__((ext_vector_type(8)));
typedef float f32x4 __attribute__((ext_vector_type(4)));

#define B_ 256
#define K_ 512
#define D_ 256
#define H_ 256
#define NROWS (B_*K_)          // 131072
#define LNEPS 1e-5f
#define NBLK 256
#define TILES (NROWS/32)       // 4096 row-tiles of 32
#define ITERS (TILES/NBLK)     // 16 per block
#define INV1024 (1.0f/1024.0f)

// Persistent-B MFMA kernel. 512 thr = 8 waves; wave w owns cols [32w,32w+32).
// w1 (h+l fp16, scaled low) in 128 VGPRs/wave, loaded once. Per iteration:
// stage 32 LN'd rows as fp16 h/l into LDS (double-buffered, XOR-swizzled),
// 3-pass split MFMA, epilogue w2-reduction + gumbel for those 32 rows.
__global__ __launch_bounds__(512, 2) void mfma_main(
    const float* __restrict__ slots, const float* __restrict__ gamma,
    const float* __restrict__ beta,  const float* __restrict__ w1,
    const float* __restrict__ b1,    const float* __restrict__ w2,
    const float* __restrict__ b2,    const float* __restrict__ u,
    float* __restrict__ out)
{
    extern __shared__ __align__(16) char smem[];   // 2*32768 A-buf + 2048 red
    float* red = (float*)(smem + 65536);

    const int t    = threadIdx.x;
    const int lane = t & 63;
    const int wv   = t >> 6;        // 0..7
    const int quad = lane >> 4;     // 0..3
    const int n16  = lane & 15;
    const int srow = t >> 4;        // 0..31 (staging row)
    const int seg  = t & 15;        // 16 d's per staging thread
    const int swzr = srow & 7;
    const int swzn = n16 & 7;
    const int cb   = wv * 32;

    // ---- persistent B fragments: B[k=quad*8+j][n=lane&15] ----
    half8 Bh[2][8], Bl[2][8];
    #pragma unroll
    for (int ct = 0; ct < 2; ++ct) {
        const int col = cb + ct*16 + n16;
        #pragma unroll
        for (int ks = 0; ks < 8; ++ks) {
            const int k0 = ks*32 + quad*8;
            half8 h, l;
            #pragma unroll
            for (int j = 0; j < 8; ++j) {
                const float w = w1[(size_t)(k0 + j)*H_ + col];
                const _Float16 hh = (_Float16)w;
                h[j] = hh;
                l[j] = (_Float16)((w - (float)hh) * 1024.0f);
            }
            Bh[ct][ks] = h; Bl[ct][ks] = l;
        }
    }
    // hoisted epilogue constants (cols fixed per lane)
    float b1v[2], w20[2], w21[2];
    #pragma unroll
    for (int ct = 0; ct < 2; ++ct) {
        const int col = cb + ct*16 + n16;
        b1v[ct] = b1[col]; w20[ct] = w2[col*2]; w21[ct] = w2[col*2+1];
    }

    const int tile0 = blockIdx.x * ITERS;

    // LN + fp16-split + swizzled LDS store of one 32-row tile
    auto ln_stage = [&](const float* xr, char* AhW, char* AlW) {
        float s = 0.f;
        #pragma unroll
        for (int j = 0; j < 16; ++j) s += xr[j];
        s += __shfl_xor(s, 1, 64); s += __shfl_xor(s, 2, 64);
        s += __shfl_xor(s, 4, 64); s += __shfl_xor(s, 8, 64);
        const float mean = s * (1.f/256.f);
        float q = 0.f;
        #pragma unroll
        for (int j = 0; j < 16; ++j) { const float d = xr[j]-mean; q += d*d; }
        q += __shfl_xor(q, 1, 64); q += __shfl_xor(q, 2, 64);
        q += __shfl_xor(q, 4, 64); q += __shfl_xor(q, 8, 64);
        const float rstd = rsqrtf(q * (1.f/256.f) + LNEPS);
        const float4* gp = (const float4*)(gamma + seg*16);
        const float4* bp = (const float4*)(beta  + seg*16);
        float gv[16], bv[16];
        #pragma unroll
        for (int i4 = 0; i4 < 4; ++i4) {
            const float4 g4 = gp[i4], b4 = bp[i4];
            gv[4*i4+0]=g4.x; gv[4*i4+1]=g4.y; gv[4*i4+2]=g4.z; gv[4*i4+3]=g4.w;
            bv[4*i4+0]=b4.x; bv[4*i4+1]=b4.y; bv[4*i4+2]=b4.z; bv[4*i4+3]=b4.w;
        }
        #pragma unroll
        for (int b = 0; b < 2; ++b) {
            half8 hh, ll;
            #pragma unroll
            for (int jj = 0; jj < 8; ++jj) {
                const int idx = b*8 + jj;
                const float x = (xr[idx]-mean)*rstd*gv[idx] + bv[idx];
                const _Float16 xh = (_Float16)x;
                hh[jj] = xh;
                ll[jj] = (_Float16)((x - (float)xh) * 1024.0f);
            }
            const int gW = ((2*seg + b) ^ swzr) * 16;
            *(half8*)(AhW + srow*512 + gW) = hh;
            *(half8*)(AlW + srow*512 + gW) = ll;
        }
    };

    // prologue: stage tile0 into buf 0
    {
        const float* sp = slots + ((size_t)tile0*32 + srow)*D_ + seg*16;
        float xr[16];
        #pragma unroll
        for (int i4 = 0; i4 < 4; ++i4) {
            const float4 v = ((const float4*)sp)[i4];
            xr[4*i4+0]=v.x; xr[4*i4+1]=v.y; xr[4*i4+2]=v.z; xr[4*i4+3]=v.w;
        }
        ln_stage(xr, smem, smem + 16384);
    }
    __syncthreads();

    for (int i = 0; i < ITERS; ++i) {
        const int p = i & 1;
        const bool have_next = (i + 1 < ITERS);

        // early global loads for next tile (latency hidden by MFMA phase)
        float xr[16];
        if (have_next) {
            const float* sp = slots + ((size_t)(tile0+i+1)*32 + srow)*D_ + seg*16;
            #pragma unroll
            for (int i4 = 0; i4 < 4; ++i4) {
                const float4 v = ((const float4*)sp)[i4];
                xr[4*i4+0]=v.x; xr[4*i4+1]=v.y; xr[4*i4+2]=v.z; xr[4*i4+3]=v.w;
            }
        }

        // ---- GEMM: 3-pass split MFMA over K=256 ----
        const char* Ah = smem + (size_t)p*32768;
        const char* Al = Ah + 16384;
        f32x4 Ch[2][2], Cl[2][2];
        #pragma unroll
        for (int rs = 0; rs < 2; ++rs)
            #pragma unroll
            for (int ct = 0; ct < 2; ++ct) { Ch[rs][ct] = (f32x4)0.f; Cl[rs][ct] = (f32x4)0.f; }

        #pragma unroll
        for (int ks = 0; ks < 8; ++ks) {
            const int go = ((ks*4 + quad) ^ swzn) * 16;
            const half8 ah0 = *(const half8*)(Ah +  n16     *512 + go);
            const half8 ah1 = *(const half8*)(Ah + (n16+16) *512 + go);
            const half8 al0 = *(const half8*)(Al +  n16     *512 + go);
            const half8 al1 = *(const half8*)(Al + (n16+16) *512 + go);
            #pragma unroll
            for (int ct = 0; ct < 2; ++ct) {
                Ch[0][ct] = __builtin_amdgcn_mfma_f32_16x16x32_f16(ah0, Bh[ct][ks], Ch[0][ct], 0,0,0);
                Ch[1][ct] = __builtin_amdgcn_mfma_f32_16x16x32_f16(ah1, Bh[ct][ks], Ch[1][ct], 0,0,0);
                Cl[0][ct] = __builtin_amdgcn_mfma_f32_16x16x32_f16(ah0, Bl[ct][ks], Cl[0][ct], 0,0,0);
                Cl[1][ct] = __builtin_amdgcn_mfma_f32_16x16x32_f16(ah1, Bl[ct][ks], Cl[1][ct], 0,0,0);
                Cl[0][ct] = __builtin_amdgcn_mfma_f32_16x16x32_f16(al0, Bh[ct][ks], Cl[0][ct], 0,0,0);
                Cl[1][ct] = __builtin_amdgcn_mfma_f32_16x16x32_f16(al1, Bh[ct][ks], Cl[1][ct], 0,0,0);
            }
        }

        // ---- epilogue: relu + w2 dot, reduce over cols ----
        #pragma unroll
        for (int rs = 0; rs < 2; ++rs) {
            #pragma unroll
            for (int reg = 0; reg < 4; ++reg) {
                float p0 = 0.f, p1 = 0.f;
                #pragma unroll
                for (int ct = 0; ct < 2; ++ct) {
                    float hv = Ch[rs][ct][reg] + Cl[rs][ct][reg]*INV1024 + b1v[ct];
                    hv = fmaxf(hv, 0.f);
                    p0 = fmaf(hv, w20[ct], p0);
                    p1 = fmaf(hv, w21[ct], p1);
                }
                p0 += __shfl_xor(p0, 1, 64); p1 += __shfl_xor(p1, 1, 64);
                p0 += __shfl_xor(p0, 2, 64); p1 += __shfl_xor(p1, 2, 64);
                p0 += __shfl_xor(p0, 4, 64); p1 += __shfl_xor(p1, 4, 64);
                p0 += __shfl_xor(p0, 8, 64); p1 += __shfl_xor(p1, 8, 64);
                if (n16 == 0) {
                    const int row = rs*16 + quad*4 + reg;
                    red[(wv*32 + row)*2 + 0] = p0;
                    red[(wv*32 + row)*2 + 1] = p1;
                }
            }
        }
        __syncthreads();

        // ---- finalize 32 rows ----
        if (t < 32) {
            const int gr = (tile0 + i)*32 + t;
            float l0 = b2[0], l1 = b2[1];
            #pragma unroll
            for (int w = 0; w < 8; ++w) {
                l0 += red[(w*32 + t)*2 + 0];
                l1 += red[(w*32 + t)*2 + 1];
            }
            const float u0 = u[2*gr + 0];
            const float u1 = u[2*gr + 1];
            const float g0 = -logf(-logf(u0));
            const float g1 = -logf(-logf(u1));
            out[gr] = ((l1 + g1) > (l0 + g0)) ? 1.f : 0.f;
            out[NROWS + gr] = 1.f / (1.f + expf(l0 - l1));
        }

        // ---- stage next tile into other buffer ----
        if (have_next) {
            char* AhW = smem + (size_t)(p^1)*32768;
            ln_stage(xr, AhW, AhW + 16384);
        }
        __syncthreads();
    }
}

// Lower-bound fixup: per batch row b, if no slot kept, set mask=1 at the
// dropped slot with max rand_key (first index on ties).
__global__ __launch_bounds__(512) void fixup(
    const float* __restrict__ rk, float* __restrict__ out)
{
    __shared__ unsigned long long best[8];
    __shared__ int cnts[8];
    const int b = blockIdx.x;
    const int k = threadIdx.x;
    const float m = out[b*K_ + k];
    const unsigned long long ball = __ballot(m != 0.f);
    const int wv = k >> 6;
    const int wcount = __popcll(ball);
    const unsigned kb = __float_as_uint(rk[b*K_ + k]);
    unsigned long long comb = ((unsigned long long)kb << 32) | (unsigned)(K_ - 1 - k);
    #pragma unroll
    for (int off = 32; off; off >>= 1) {
        unsigned long long o = __shfl_down(comb, off, 64);
        if (o > comb) comb = o;
    }
    if ((k & 63) == 0) { best[wv] = comb; cnts[wv] = wcount; }
    __syncthreads();
    if (k == 0) {
        int tot = 0; unsigned long long bc = 0;
        #pragma unroll
        for (int w = 0; w < 8; ++w) { tot += cnts[w]; if (best[w] > bc) bc = best[w]; }
        if (tot == 0) {
            const int kbest = (K_ - 1) - (int)(bc & 0xffffffffu);
            out[b*K_ + kbest] = 1.f;
        }
    }
}

extern "C" void kernel_launch(void* const* d_in, const int* in_sizes, int n_in,
                              void* d_out, int out_size, void* d_ws, size_t ws_size,
                              hipStream_t stream) {
    const float* slots = (const float*)d_in[0];
    const float* gamma = (const float*)d_in[1];
    const float* beta  = (const float*)d_in[2];
    const float* w1    = (const float*)d_in[3];
    const float* b1    = (const float*)d_in[4];
    const float* w2    = (const float*)d_in[5];
    const float* b2    = (const float*)d_in[6];
    const float* u     = (const float*)d_in[7];
    const float* rk    = (const float*)d_in[8];
    float* out = (float*)d_out;

    const size_t lds_bytes = 2*32768 + 2048;
    hipLaunchKernelGGL(mfma_main, dim3(NBLK), dim3(512), lds_bytes, stream,
                       slots, gamma, beta, w1, b1, w2, b2, u, out);
    hipLaunchKernelGGL(fixup, dim3(B_), dim3(512), 0, stream, rk, out);
}